// Round 1
// baseline (570.562 us; speedup 1.0000x reference)
//
#include <hip/hip_runtime.h>
#include <stdint.h>

// ---------------- problem constants ----------------
#define T_TREES 10
#define IN_DIM  2048
#define BATCH   16384
#define CLASSES 1000
#define NDEC    255
#define NPAD    256          // decisions padded to 256
#define K2DIM   (T_TREES * NPAD)  // 2560
#define NPADC   1024         // classes padded to 1024

typedef unsigned short u16;
typedef float floatx4 __attribute__((ext_vector_type(4)));
typedef __bf16 bf16x8 __attribute__((ext_vector_type(8)));

// ---------------- helpers ----------------
__device__ __forceinline__ u16 f2bf(float f) {
    union { float f; uint32_t u; } v; v.f = f;
    uint32_t u = v.u;
    return (u16)((u + 0x7FFFu + ((u >> 16) & 1u)) >> 16);   // RNE
}
__device__ __forceinline__ float bf2f(u16 h) {
    union { uint32_t u; float f; } v; v.u = ((uint32_t)h) << 16;
    return v.f;
}

// async global->LDS, 16B per lane. LDS dest is wave-uniform base; HW writes
// lane i at base + i*16.
__device__ __forceinline__ void gld16(u16* lds_p, const u16* g) {
    __builtin_amdgcn_global_load_lds(
        (__attribute__((address_space(1))) const void*)g,
        (__attribute__((address_space(3))) void*)lds_p,
        16, 0, 0);
}

// ---------------- kernel 0: x fp32 -> bf16 ----------------
__global__ __launch_bounds__(256) void cast_x_k(const float4* __restrict__ x,
                                                uint2* __restrict__ xb) {
    int i = blockIdx.x * 256 + threadIdx.x;   // grid sized exactly
    float4 v = x[i];
    uint2 o;
    o.x = (uint32_t)f2bf(v.x) | ((uint32_t)f2bf(v.y) << 16);
    o.y = (uint32_t)f2bf(v.z) | ((uint32_t)f2bf(v.w) << 16);
    xb[i] = o;
}

// ---------------- kernel 1: w_d [t,i,255] fp32 -> wdT [t,256,2048] bf16 ----
__global__ void transpose_wd_k(const float* __restrict__ wd, u16* __restrict__ wdT) {
    __shared__ float tile[32][33];
    int tx = threadIdx.x, ty = threadIdx.y;
    int t = blockIdx.z;
    int i0 = blockIdx.x * 32, d0 = blockIdx.y * 32;
#pragma unroll
    for (int r = 0; r < 4; ++r) {
        int i = i0 + ty + r * 8;
        int d = d0 + tx;
        float v = (d < NDEC) ? wd[((size_t)t * IN_DIM + i) * NDEC + d] : 0.0f;
        tile[ty + r * 8][tx] = v;
    }
    __syncthreads();
#pragma unroll
    for (int r = 0; r < 4; ++r) {
        int dd = d0 + ty + r * 8;
        int ii = i0 + tx;
        wdT[((size_t)t * NPAD + dd) * IN_DIM + ii] = f2bf(tile[tx][ty + r * 8]);
    }
}

// ------- kernel 2: softmax(w_l) rows, fold leaf pairs, *0.1 -> B2 [2560,1024] bf16
__global__ __launch_bounds__(256) void softmax_fold_k(const float* __restrict__ wl,
                                                      u16* __restrict__ B2) {
    int wid = threadIdx.x >> 6, lane = threadIdx.x & 63;
    int idx = blockIdx.x * 4 + wid;          // 0..2559 = t*256 + m
    int t = idx >> 8, m = idx & 255;
    const float* r0 = wl + ((size_t)t * 512 + 2 * m) * CLASSES;
    const float* r1 = r0 + CLASSES;
    float v0[16], v1[16];
    float mx0 = -3.0e38f, mx1 = -3.0e38f;
#pragma unroll
    for (int j = 0; j < 16; ++j) {
        int c = lane + 64 * j;
        float a = (c < CLASSES) ? r0[c] : -3.0e38f;
        float b = (c < CLASSES) ? r1[c] : -3.0e38f;
        v0[j] = a; v1[j] = b;
        mx0 = fmaxf(mx0, a); mx1 = fmaxf(mx1, b);
    }
#pragma unroll
    for (int o = 32; o > 0; o >>= 1) {
        mx0 = fmaxf(mx0, __shfl_xor(mx0, o));
        mx1 = fmaxf(mx1, __shfl_xor(mx1, o));
    }
    float s0 = 0.f, s1 = 0.f;
#pragma unroll
    for (int j = 0; j < 16; ++j) {
        int c = lane + 64 * j;
        float e0 = (c < CLASSES) ? __expf(v0[j] - mx0) : 0.f;
        float e1 = (c < CLASSES) ? __expf(v1[j] - mx1) : 0.f;
        v0[j] = e0; v1[j] = e1; s0 += e0; s1 += e1;
    }
#pragma unroll
    for (int o = 32; o > 0; o >>= 1) { s0 += __shfl_xor(s0, o); s1 += __shfl_xor(s1, o); }
    float i0 = 0.1f / s0, i1 = 0.1f / s1;
#pragma unroll
    for (int j = 0; j < 16; ++j) {
        int c = lane + 64 * j;               // covers 0..1023 exactly
        float v = (c < CLASSES) ? (v0[j] * i0 + v1[j] * i1) : 0.f;
        B2[(size_t)idx * NPADC + c] = f2bf(v);
    }
}

// ---------------- kernel 3: B2 [2560,1024] -> B2t [1024,2560] bf16 ----------
__global__ void transpose_b2_k(const u16* __restrict__ B2, u16* __restrict__ B2t) {
    __shared__ u16 tile[32][33];
    int tx = threadIdx.x, ty = threadIdx.y;
    int k0 = blockIdx.x * 32, c0 = blockIdx.y * 32;
#pragma unroll
    for (int r = 0; r < 4; ++r)
        tile[ty + r * 8][tx] = B2[(size_t)(k0 + ty + r * 8) * NPADC + c0 + tx];
    __syncthreads();
#pragma unroll
    for (int r = 0; r < 4; ++r)
        B2t[(size_t)(c0 + ty + r * 8) * K2DIM + k0 + tx] = tile[tx][ty + r * 8];
}

// ======================================================================
// 256x256-tile, BK=64, 8-wave (2Mx4N), 8-phase counted-vmcnt GEMM template.
// C = A[M,K] @ B[N,K]^T.   EPI=0: sigmoid -> bf16, ldc=K2DIM (GEMM1)
//                          EPI=1: fp32 store, cols<CLASSES   (GEMM2)
//
// LDS = ring of 8 half-tile slots (each 128 rows x 64 cols bf16 = 16 KB).
// Half-tile order per K-tile t: [B0, B1, A0, A1] -> slot (4t+o) % 8.
// Staging leads consumption by 7 half-tiles; ONE vmcnt(6) per K-tile
// (vmcnt(0) only entering the last tile).  Swizzle: phys 16B-seg =
// logical ^ (row&7); inverse applied on the per-lane GLOBAL src so LDS
// dest stays linear (global_load_lds requirement).  ds_read_b128 frags
// then spread 64 lanes uniformly over all 32 banks (0 conflicts).
//
// Per tile (4 phases x 16 MFMA), per-wave ledger (lgkm in-flight):
//   p0: rd q1(4)            -> lgkmcnt(4)  [waits prev p3's 12]  MFMA q0
//   p1: rd q2(4)+q3(4)      -> lgkmcnt(8)  [waits q1]            MFMA q1
//   p2:                     -> lgkmcnt(0)  [publishes q2+q3]     MFMA q2
//   p3: stage A0; vmcnt(6); BAR; rd next-tile B(8)+q0(4);        MFMA q3
// Every slot's reads are lgkm-published >=1 barrier before its re-staging.
// ======================================================================

#define WAITLGKM_(n) asm volatile("s_waitcnt lgkmcnt(" #n ")" ::: "memory")
#define WAITLGKM(n) WAITLGKM_(n)
#define WAITVM_(n) asm volatile("s_waitcnt vmcnt(" #n ")" ::: "memory")
#define WAITVM(n) WAITVM_(n)
#define SB  __builtin_amdgcn_sched_barrier(0)
#define BAR __builtin_amdgcn_s_barrier()

template<int NT, int EPI>
__global__ __launch_bounds__(512, 2) void gemm8p(const u16* __restrict__ A,
                                                 const u16* __restrict__ B,
                                                 void* __restrict__ Cout) {
    constexpr int K = NT * 64;
    __shared__ __align__(16) u16 lds[8 * 8192];

    const int tid  = threadIdx.x;
    const int wid  = tid >> 6;
    const int lane = tid & 63;
    const int wm = wid >> 2, wn = wid & 3;      // 2 x 4 wave grid
    const int quad = lane >> 4, t16 = lane & 15;

    const size_t m0 = (size_t)blockIdx.x * 256;
    const size_t n0 = (size_t)blockIdx.y * 256;
    const u16* __restrict__ Ag = A + m0 * (size_t)K;
    const u16* __restrict__ Bg = B + n0 * (size_t)K;

    // staging: per issue (512 thr = 64 rows x 8 segs), wave w owns rows w*8..+7.
    // per-lane global offset: row part + inverse-swizzled 16B segment.
    const uint32_t stOff = (uint32_t)((wid * 8 + (lane >> 3)) * K)
                         + (uint32_t)(((lane & 7) ^ ((lane >> 3) & 7)) * 8);
    const uint32_t stLds = (uint32_t)(wid * 8 * 64);   // elems, wave-uniform

#define STAGE(slot, o, tk) do { \
    const u16* gp_ = (((o) < 2) ? Bg : Ag) + ((size_t)(((o) & 1) * 128) * K) \
                   + ((size_t)(tk) * 64) + stOff; \
    gld16(&lds[(slot) * 8192 + stLds], gp_); \
    gld16(&lds[(slot) * 8192 + stLds + 4096], gp_ + (size_t)64 * K); \
  } while (0)

    // read-side addresses (elems). rl&7 == t16&7 for all frags.
#define AOFF(P, mi, kk) (((P) * 4 + 2 + wm) * 8192 + ((mi) * 16 + t16) * 64 \
                         + ((((kk) * 4 + quad) ^ (t16 & 7)) * 8))
#define BOFF(P, ni, kk) (((P) * 4 + ((wn * 64 + (ni) * 16) >> 7)) * 8192 \
                         + (((wn * 64 + (ni) * 16) & 127) + t16) * 64 \
                         + ((((kk) * 4 + quad) ^ (t16 & 7)) * 8))

#define RD2(dst, P, mi0) do { \
    dst[0][0] = *(const bf16x8*)&lds[AOFF(P, (mi0),     0)]; \
    dst[0][1] = *(const bf16x8*)&lds[AOFF(P, (mi0),     1)]; \
    dst[1][0] = *(const bf16x8*)&lds[AOFF(P, (mi0) + 1, 0)]; \
    dst[1][1] = *(const bf16x8*)&lds[AOFF(P, (mi0) + 1, 1)]; \
  } while (0)

#define RDB(dst, P) do { \
    _Pragma("unroll") \
    for (int ni_ = 0; ni_ < 4; ++ni_) { \
      dst[ni_][0] = *(const bf16x8*)&lds[BOFF(P, ni_, 0)]; \
      dst[ni_][1] = *(const bf16x8*)&lds[BOFF(P, ni_, 1)]; \
    } \
  } while (0)

#define MFQ(p, aq, bs) do { \
    _Pragma("unroll") \
    for (int kk_ = 0; kk_ < 2; ++kk_) { \
      _Pragma("unroll") \
      for (int ni_ = 0; ni_ < 4; ++ni_) { \
        acc[2*(p)][ni_]   = __builtin_amdgcn_mfma_f32_16x16x32_bf16( \
            aq[0][kk_], bs[ni_][kk_], acc[2*(p)][ni_], 0, 0, 0); \
        acc[2*(p)+1][ni_] = __builtin_amdgcn_mfma_f32_16x16x32_bf16( \
            aq[1][kk_], bs[ni_][kk_], acc[2*(p)+1][ni_], 0, 0, 0); \
      } \
    } \
  } while (0)

    floatx4 acc[8][4];
#pragma unroll
    for (int i = 0; i < 8; ++i)
#pragma unroll
        for (int j = 0; j < 4; ++j) acc[i][j] = (floatx4){0.f, 0.f, 0.f, 0.f};

    // ping-pong frag sets (liveness: at most one + the filling one live)
    bf16x8 bA[4][2], bB[4][2];        // B frags, whole tile
    bf16x8 a0A[2][2], a0B[2][2];      // A quad0 (read at prev tile's p3)
    bf16x8 aT1[2][2], aT2[2][2], aT3[2][2];

    // ---- prologue: stage tile0 {B0,B1,A0,A1} + tile1 {B0,B1,A0} ----
    STAGE(0, 0, 0); STAGE(1, 1, 0); STAGE(2, 2, 0); STAGE(3, 3, 0);
    STAGE(4, 0, 1); STAGE(5, 1, 1); STAGE(6, 2, 1);
    WAITVM(6);                 // tile 0 fully landed (14 issued - 6)
    BAR; SB;
    RDB(bA, 0); RD2(a0A, 0, 0);   // 12 reads in flight (steady-state entry)

#define TILE(P, t, S_A1, S_T2, NEXTF, VMN, bcur, bnxt, a0c, a0n) do { \
    /* phase 0 */ \
    RD2(aT1, P, 2); \
    if (S_A1) { STAGE((1 - (P)) * 4 + 3, 3, (t) + 1); } \
    WAITLGKM(4); SB; \
    __builtin_amdgcn_s_setprio(1); MFQ(0, a0c, bcur); __builtin_amdgcn_s_setprio(0); \
    BAR; SB; \
    /* phase 1 */ \
    RD2(aT2, P, 4); RD2(aT3, P, 6); \
    if (S_T2) { STAGE((P) * 4 + 0, 0, (t) + 2); } \
    WAITLGKM(8); SB; \
    __builtin_amdgcn_s_setprio(1); MFQ(1, aT1, bcur); __builtin_amdgcn_s_setprio(0); \
    BAR; SB; \
    /* phase 2 */ \
    if (S_T2) { STAGE((P) * 4 + 1, 1, (t) + 2); } \
    WAITLGKM(0); SB; \
    __builtin_amdgcn_s_setprio(1); MFQ(2, aT2, bcur); __builtin_amdgcn_s_setprio(0); \
    BAR; SB; \
    /* phase 3 */ \
    if (S_T2) { STAGE((P) * 4 + 2, 2, (t) + 2); } \
    if (NEXTF) { WAITVM(VMN); } \
    BAR; SB; \
    if (NEXTF) { RDB(bnxt, 1 - (P)); RD2(a0n, 1 - (P), 0); SB; } \
    __builtin_amdgcn_s_setprio(1); MFQ(3, aT3, bcur); __builtin_amdgcn_s_setprio(0); \
    BAR; SB; \
  } while (0)

    int t = 0;
#pragma unroll 1
    for (int it = 0; it < NT / 2 - 1; ++it, t += 2) {
        TILE(0, t,     true, true, true, 6, bA, bB, a0A, a0B);
        TILE(1, t + 1, true, true, true, 6, bB, bA, a0B, a0A);
    }
    // tail: tiles NT-2, NT-1 (no staging beyond end; vmcnt(0) before last)
    TILE(0, t,     true,  false, true,  0, bA, bB, a0A, a0B);
    TILE(1, t + 1, false, false, false, 0, bB, bA, a0B, a0A);

    // ---- epilogue.  C/D layout: col = lane&15, row = (lane>>4)*4 + reg ----
    if constexpr (EPI == 0) {
        u16* C = (u16*)Cout;
#pragma unroll
        for (int mi = 0; mi < 8; ++mi)
#pragma unroll
            for (int r = 0; r < 4; ++r) {
                const size_t row = m0 + wm * 128 + mi * 16 + quad * 4 + r;
#pragma unroll
                for (int ni = 0; ni < 4; ++ni) {
                    const int col = (int)n0 + wn * 64 + ni * 16 + t16;
                    float v = acc[mi][ni][r];
                    float p = 1.0f / (1.0f + __expf(-v));
                    C[row * (size_t)K2DIM + col] = f2bf(p);
                }
            }
    } else {
        float* C = (float*)Cout;
#pragma unroll
        for (int mi = 0; mi < 8; ++mi)
#pragma unroll
            for (int r = 0; r < 4; ++r) {
                const size_t row = m0 + wm * 128 + mi * 16 + quad * 4 + r;
#pragma unroll
                for (int ni = 0; ni < 4; ++ni) {
                    const int col = (int)n0 + wn * 64 + ni * 16 + t16;
                    if (col < CLASSES)
                        C[row * (size_t)CLASSES + col] = acc[mi][ni][r];
                }
            }
    }
#undef TILE
#undef MFQ
#undef RDB
#undef RD2
#undef BOFF
#undef AOFF
#undef STAGE
}

// ---------------- kernel 5: leaf path products ------------------------------
// dp [b, t*256+d] bf16 decision probs -> lp [b, t*256+m] bf16 (m = folded leaf)
// factor(n,m): dec = (1<<n)-1 + (m>>(8-n)), side = (m>>(7-n))&1
__global__ __launch_bounds__(256) void leafprod_k(const u16* __restrict__ dp,
                                                  u16* __restrict__ lp) {
    __shared__ float P[4][256];
    int wid = threadIdx.x >> 6, lane = threadIdx.x & 63;
    int idx = blockIdx.x * 4 + wid;          // 0..163839 = t*16384 + b
    int t = idx >> 14, b = idx & 16383;
    const u16* row = dp + (size_t)b * K2DIM + t * NPAD;
#pragma unroll
    for (int j = 0; j < 4; ++j)
        P[wid][lane + 64 * j] = bf2f(row[lane + 64 * j]);
    __syncthreads();
#pragma unroll
    for (int j = 0; j < 4; ++j) {
        int m = lane + 64 * j;
        float prod = 1.0f;
#pragma unroll
        for (int n = 0; n < 8; ++n) {
            int dec  = (1 << n) - 1 + (m >> (8 - n));
            int side = (m >> (7 - n)) & 1;
            float p  = P[wid][dec];
            prod *= side ? (1.0f - p) : p;
        }
        lp[(size_t)b * K2DIM + t * NPAD + m] = f2bf(prod);
    }
}

// ---------------- launch -----------------------------------------------------
extern "C" void kernel_launch(void* const* d_in, const int* in_sizes, int n_in,
                              void* d_out, int out_size, void* d_ws, size_t ws_size,
                              hipStream_t stream) {
    const float* x   = (const float*)d_in[0];
    const float* w_d = (const float*)d_in[1];
    const float* w_l = (const float*)d_in[2];
    float* out = (float*)d_out;

    // workspace layout (173,015,040 B total, with aliasing):
    //   [0, 5.24MB)        B2t  (alive softmax..gemm2)
    //   region = +5.24MB, 83.9MB:
    //       xb (67.1MB) | wdT (10.5MB) | B2 (5.24MB)   -- dead after gemm1
    //       lp (83.9MB) aliases the region, written after gemm1
    //   [+89.1MB, +173MB)  dp (83.9MB)
    char* w = (char*)d_ws;
    u16* B2t = (u16*)w;
    char* region = w + 5242880;
    u16* xb  = (u16*)region;
    u16* wdT = (u16*)(region + 67108864);
    u16* B2  = (u16*)(region + 67108864 + 10485760);
    u16* lp  = (u16*)region;
    u16* dp  = (u16*)(region + 83886080);

    cast_x_k<<<32768, 256, 0, stream>>>((const float4*)x, (uint2*)xb);
    transpose_wd_k<<<dim3(64, 8, T_TREES), dim3(32, 8), 0, stream>>>(w_d, wdT);
    softmax_fold_k<<<640, 256, 0, stream>>>(w_l, B2);
    transpose_b2_k<<<dim3(80, 32), dim3(32, 8), 0, stream>>>(B2, B2t);
    // GEMM1 (8-phase 256^2): [16384,2048] x [2560,2048]^T -> sigmoid -> dp bf16
    gemm8p<32, 0><<<dim3(64, 10), 512, 0, stream>>>(xb, wdT, dp);
    leafprod_k<<<40960, 256, 0, stream>>>(dp, lp);
    // GEMM2 (8-phase 256^2): [16384,2560] x [1024,2560]^T -> out fp32 (cols<1000)
    gemm8p<40, 1><<<dim3(64, 4), 512, 0, stream>>>(lp, B2t, out);
}

// Round 2
// 522.510 us; speedup vs baseline: 1.0920x; 1.0920x over previous
//
#include <hip/hip_runtime.h>
#include <stdint.h>

// ---------------- problem constants ----------------
#define T_TREES 10
#define IN_DIM  2048
#define BATCH   16384
#define CLASSES 1000
#define NDEC    255
#define NPAD    256          // decisions padded to 256
#define K2DIM   (T_TREES * NPAD)  // 2560
#define NPADC   1024         // classes padded to 1024

typedef unsigned short u16;
typedef float floatx4 __attribute__((ext_vector_type(4)));
typedef __bf16 bf16x8 __attribute__((ext_vector_type(8)));

// ---------------- helpers ----------------
__device__ __forceinline__ u16 f2bf(float f) {
    union { float f; uint32_t u; } v; v.f = f;
    uint32_t u = v.u;
    return (u16)((u + 0x7FFFu + ((u >> 16) & 1u)) >> 16);   // RNE
}
__device__ __forceinline__ float bf2f(u16 h) {
    union { uint32_t u; float f; } v; v.u = ((uint32_t)h) << 16;
    return v.f;
}

// async global->LDS, 16B per lane. LDS dest is wave-uniform base; HW writes
// lane i at base + i*16.
__device__ __forceinline__ void gld16(u16* lds_p, const u16* g) {
    __builtin_amdgcn_global_load_lds(
        (__attribute__((address_space(1))) const void*)g,
        (__attribute__((address_space(3))) void*)lds_p,
        16, 0, 0);
}

// ---------------- kernel 0: x fp32 -> bf16 ----------------
__global__ __launch_bounds__(256) void cast_x_k(const float4* __restrict__ x,
                                                uint2* __restrict__ xb) {
    int i = blockIdx.x * 256 + threadIdx.x;   // grid sized exactly
    float4 v = x[i];
    uint2 o;
    o.x = (uint32_t)f2bf(v.x) | ((uint32_t)f2bf(v.y) << 16);
    o.y = (uint32_t)f2bf(v.z) | ((uint32_t)f2bf(v.w) << 16);
    xb[i] = o;
}

// ---------------- kernel 1: w_d [t,i,255] fp32 -> wdT [t,256,2048] bf16 ----
__global__ void transpose_wd_k(const float* __restrict__ wd, u16* __restrict__ wdT) {
    __shared__ float tile[32][33];
    int tx = threadIdx.x, ty = threadIdx.y;
    int t = blockIdx.z;
    int i0 = blockIdx.x * 32, d0 = blockIdx.y * 32;
#pragma unroll
    for (int r = 0; r < 4; ++r) {
        int i = i0 + ty + r * 8;
        int d = d0 + tx;
        float v = (d < NDEC) ? wd[((size_t)t * IN_DIM + i) * NDEC + d] : 0.0f;
        tile[ty + r * 8][tx] = v;
    }
    __syncthreads();
#pragma unroll
    for (int r = 0; r < 4; ++r) {
        int dd = d0 + ty + r * 8;
        int ii = i0 + tx;
        wdT[((size_t)t * NPAD + dd) * IN_DIM + ii] = f2bf(tile[tx][ty + r * 8]);
    }
}

// ------- kernel 2: softmax(w_l) rows, fold leaf pairs, *0.1 -> B2 [2560,1024] bf16
__global__ __launch_bounds__(256) void softmax_fold_k(const float* __restrict__ wl,
                                                      u16* __restrict__ B2) {
    int wid = threadIdx.x >> 6, lane = threadIdx.x & 63;
    int idx = blockIdx.x * 4 + wid;          // 0..2559 = t*256 + m
    int t = idx >> 8, m = idx & 255;
    const float* r0 = wl + ((size_t)t * 512 + 2 * m) * CLASSES;
    const float* r1 = r0 + CLASSES;
    float v0[16], v1[16];
    float mx0 = -3.0e38f, mx1 = -3.0e38f;
#pragma unroll
    for (int j = 0; j < 16; ++j) {
        int c = lane + 64 * j;
        float a = (c < CLASSES) ? r0[c] : -3.0e38f;
        float b = (c < CLASSES) ? r1[c] : -3.0e38f;
        v0[j] = a; v1[j] = b;
        mx0 = fmaxf(mx0, a); mx1 = fmaxf(mx1, b);
    }
#pragma unroll
    for (int o = 32; o > 0; o >>= 1) {
        mx0 = fmaxf(mx0, __shfl_xor(mx0, o));
        mx1 = fmaxf(mx1, __shfl_xor(mx1, o));
    }
    float s0 = 0.f, s1 = 0.f;
#pragma unroll
    for (int j = 0; j < 16; ++j) {
        int c = lane + 64 * j;
        float e0 = (c < CLASSES) ? __expf(v0[j] - mx0) : 0.f;
        float e1 = (c < CLASSES) ? __expf(v1[j] - mx1) : 0.f;
        v0[j] = e0; v1[j] = e1; s0 += e0; s1 += e1;
    }
#pragma unroll
    for (int o = 32; o > 0; o >>= 1) { s0 += __shfl_xor(s0, o); s1 += __shfl_xor(s1, o); }
    float i0 = 0.1f / s0, i1 = 0.1f / s1;
#pragma unroll
    for (int j = 0; j < 16; ++j) {
        int c = lane + 64 * j;               // covers 0..1023 exactly
        float v = (c < CLASSES) ? (v0[j] * i0 + v1[j] * i1) : 0.f;
        B2[(size_t)idx * NPADC + c] = f2bf(v);
    }
}

// ---------------- kernel 3: B2 [2560,1024] -> B2t [1024,2560] bf16 ----------
__global__ void transpose_b2_k(const u16* __restrict__ B2, u16* __restrict__ B2t) {
    __shared__ u16 tile[32][33];
    int tx = threadIdx.x, ty = threadIdx.y;
    int k0 = blockIdx.x * 32, c0 = blockIdx.y * 32;
#pragma unroll
    for (int r = 0; r < 4; ++r)
        tile[ty + r * 8][tx] = B2[(size_t)(k0 + ty + r * 8) * NPADC + c0 + tx];
    __syncthreads();
#pragma unroll
    for (int r = 0; r < 4; ++r)
        B2t[(size_t)(c0 + ty + r * 8) * K2DIM + k0 + tx] = tile[tx][ty + r * 8];
}

// ======================================================================
// 256x256-tile, BK=64, 8-wave (2Mx4N), m201-style phased GEMM template.
// C = A[M,K] @ B[N,K]^T.   EPI=0: sigmoid -> bf16, ldc=K2DIM (GEMM1)
//                          EPI=1: fp32 store, cols<CLASSES   (GEMM2)
//
// LDS = 8 half-tile slots (128 rows x 64 cols bf16 = 16 KB each), double
// buffered by tile parity P: slots P*4+{0:B0,1:B1,2:A0,3:A1}.
//
// Per K-tile: 4 phases {mi-half x kk}, each phase =
//     [ds_read own frags (4 or 8); stage] BAR; lgkmcnt(0); SB;
//     setprio(1); 16 MFMA; setprio(0); BAR;
// Frags are consumed in the phase they are read (max live frags = 8 ->
// ~64 arch VGPRs; round-1's cross-phase liveness needed ~144 and choked
// the allocator at the 128-VGPR cap).  ds_read latency hides under the
// OTHER wave's setprio'd MFMA on the same SIMD (2 waves/SIMD).
//
// Stage/hazard ledger (all compile-time):
//   A(t) read in all 4 phases  -> A(t+1) staged at tile t P0 (after t-1
//     P3's readers are lgkm-published and barrier-separated).
//   B(t) read at P0(kk0), P2(kk1) -> B(t+2) staged at tile t P3.
//   One WAITVM(4) per tile at P3 (after B stage issue): retires
//   A(t+1)+B(t+1) (8 oldest loads), leaves B(t+2) (4) in flight. BAR
//   after the wait => every wave's stages landed before any t+1 read.
//   Swizzle: phys 16B-seg = logical ^ (row&7), inverse pre-applied on the
//   per-lane GLOBAL src (LDS dest stays linear for global_load_lds).
// ======================================================================

#define WAITLGKM_(n) asm volatile("s_waitcnt lgkmcnt(" #n ")" ::: "memory")
#define WAITLGKM(n) WAITLGKM_(n)
#define WAITVM_(n) asm volatile("s_waitcnt vmcnt(" #n ")" ::: "memory")
#define WAITVM(n) WAITVM_(n)
#define SB  __builtin_amdgcn_sched_barrier(0)
#define BAR __builtin_amdgcn_s_barrier()

template<int NT, int EPI>
__global__ __launch_bounds__(512, 2) void gemm8p(const u16* __restrict__ A,
                                                 const u16* __restrict__ B,
                                                 void* __restrict__ Cout) {
    constexpr int K = NT * 64;
    __shared__ __align__(16) u16 lds[8 * 8192];

    const int tid  = threadIdx.x;
    const int wid  = tid >> 6;
    const int lane = tid & 63;
    const int wm = wid >> 2, wn = wid & 3;      // 2 x 4 wave grid
    const int quad = lane >> 4, t16 = lane & 15;

    const size_t m0 = (size_t)blockIdx.x * 256;
    const size_t n0 = (size_t)blockIdx.y * 256;
    const u16* __restrict__ Ag = A + m0 * (size_t)K;
    const u16* __restrict__ Bg = B + n0 * (size_t)K;

    // staging: per gld16 issue (512 thr = 64 rows x 8 segs), wave w owns
    // rows w*8..w*8+7 of the half-tile.  Global src seg is inverse-swizzled.
    const uint32_t stOff = (uint32_t)((wid * 8 + (lane >> 3)) * K)
                         + (uint32_t)(((lane & 7) ^ ((lane >> 3) & 7)) * 8);
    const uint32_t stLds = (uint32_t)(wid * 8 * 64);   // elems, wave-uniform

#define STAGE(slot, o, tk) do { \
    const u16* gp_ = (((o) < 2) ? Bg : Ag) + ((size_t)(((o) & 1) * 128) * K) \
                   + ((size_t)(tk) * 64) + stOff; \
    gld16(&lds[(slot) * 8192 + stLds], gp_); \
    gld16(&lds[(slot) * 8192 + stLds + 4096], gp_ + (size_t)64 * K); \
  } while (0)

    // read-side element offsets; swizzled seg = (kk*4+quad) ^ (t16&7)
#define AOFF(P, mi, kk) (((P) * 4 + 2 + wm) * 8192 + ((mi) * 16 + t16) * 64 \
                         + ((((kk) * 4 + quad) ^ (t16 & 7)) * 8))
#define BOFF(P, ni, kk) (((P) * 4 + (wn >> 1)) * 8192 \
                         + ((wn & 1) * 64 + (ni) * 16 + t16) * 64 \
                         + ((((kk) * 4 + quad) ^ (t16 & 7)) * 8))

#define RDA(P, mb, kk) do { \
    aF[0] = *(const bf16x8*)&lds[AOFF(P, (mb) + 0, kk)]; \
    aF[1] = *(const bf16x8*)&lds[AOFF(P, (mb) + 1, kk)]; \
    aF[2] = *(const bf16x8*)&lds[AOFF(P, (mb) + 2, kk)]; \
    aF[3] = *(const bf16x8*)&lds[AOFF(P, (mb) + 3, kk)]; \
  } while (0)

#define RDBF(P, kk) do { \
    bF[0] = *(const bf16x8*)&lds[BOFF(P, 0, kk)]; \
    bF[1] = *(const bf16x8*)&lds[BOFF(P, 1, kk)]; \
    bF[2] = *(const bf16x8*)&lds[BOFF(P, 2, kk)]; \
    bF[3] = *(const bf16x8*)&lds[BOFF(P, 3, kk)]; \
  } while (0)

#define MF16(mb) do { \
    _Pragma("unroll") \
    for (int ni_ = 0; ni_ < 4; ++ni_) { \
      _Pragma("unroll") \
      for (int j_ = 0; j_ < 4; ++j_) { \
        acc[(mb) + j_][ni_] = __builtin_amdgcn_mfma_f32_16x16x32_bf16( \
            aF[j_], bF[ni_], acc[(mb) + j_][ni_], 0, 0, 0); \
      } \
    } \
  } while (0)

    floatx4 acc[8][4];
#pragma unroll
    for (int i = 0; i < 8; ++i)
#pragma unroll
        for (int j = 0; j < 4; ++j) acc[i][j] = (floatx4){0.f, 0.f, 0.f, 0.f};

    bf16x8 aF[4], bF[4];

    // ---- prologue: stage tile0 {B0,B1,A0,A1} + tile1 {B0,B1} ----
    STAGE(0, 0, 0); STAGE(1, 1, 0); STAGE(2, 2, 0); STAGE(3, 3, 0);
    STAGE(4, 0, 1); STAGE(5, 1, 1);
    WAITVM(4);                 // tile0 fully landed; B(1) in flight
    BAR;

#define TILE(P, t, SA, SBG, HASW, WN) do { \
    /* P0: mi 0-3, kk0 (A 4 + B 4 reads); stage A(t+1) */ \
    RDA(P, 0, 0); RDBF(P, 0); \
    if (SA) { STAGE((1 - (P)) * 4 + 2, 2, (t) + 1); \
              STAGE((1 - (P)) * 4 + 3, 3, (t) + 1); } \
    BAR; WAITLGKM(0); SB; \
    __builtin_amdgcn_s_setprio(1); MF16(0); __builtin_amdgcn_s_setprio(0); \
    BAR; \
    /* P1: mi 4-7, kk0 (A 4 reads) */ \
    RDA(P, 4, 0); \
    BAR; WAITLGKM(0); SB; \
    __builtin_amdgcn_s_setprio(1); MF16(4); __builtin_amdgcn_s_setprio(0); \
    BAR; \
    /* P2: mi 0-3, kk1 (A 4 + B 4 reads) */ \
    RDA(P, 0, 1); RDBF(P, 1); \
    BAR; WAITLGKM(0); SB; \
    __builtin_amdgcn_s_setprio(1); MF16(0); __builtin_amdgcn_s_setprio(0); \
    BAR; \
    /* P3: mi 4-7, kk1 (A 4 reads); stage B(t+2); counted vmcnt */ \
    RDA(P, 4, 1); \
    if (SBG) { STAGE((P) * 4 + 0, 0, (t) + 2); \
               STAGE((P) * 4 + 1, 1, (t) + 2); } \
    if (HASW) { WAITVM(WN); } \
    BAR; WAITLGKM(0); SB; \
    __builtin_amdgcn_s_setprio(1); MF16(4); __builtin_amdgcn_s_setprio(0); \
    BAR; \
  } while (0)

    int t = 0;
#pragma unroll 1
    for (int it = 0; it < NT / 2 - 1; ++it, t += 2) {
        TILE(0, t,     true, true, true, 4);
        TILE(1, t + 1, true, true, true, 4);
    }
    // tail: tile NT-2 stages A(NT-1) then drains; NT-1 stages nothing
    TILE(0, NT - 2, true,  false, true,  0);
    TILE(1, NT - 1, false, false, false, 0);

    // ---- epilogue.  C/D layout: col = lane&15, row = (lane>>4)*4 + reg ----
    if constexpr (EPI == 0) {
        u16* C = (u16*)Cout;
#pragma unroll
        for (int mi = 0; mi < 8; ++mi)
#pragma unroll
            for (int r = 0; r < 4; ++r) {
                const size_t row = m0 + wm * 128 + mi * 16 + quad * 4 + r;
#pragma unroll
                for (int ni = 0; ni < 4; ++ni) {
                    const int col = (int)n0 + wn * 64 + ni * 16 + t16;
                    float v = acc[mi][ni][r];
                    float p = 1.0f / (1.0f + __expf(-v));
                    C[row * (size_t)K2DIM + col] = f2bf(p);
                }
            }
    } else {
        float* C = (float*)Cout;
#pragma unroll
        for (int mi = 0; mi < 8; ++mi)
#pragma unroll
            for (int r = 0; r < 4; ++r) {
                const size_t row = m0 + wm * 128 + mi * 16 + quad * 4 + r;
#pragma unroll
                for (int ni = 0; ni < 4; ++ni) {
                    const int col = (int)n0 + wn * 64 + ni * 16 + t16;
                    if (col < CLASSES)
                        C[row * (size_t)CLASSES + col] = acc[mi][ni][r];
                }
            }
    }
#undef TILE
#undef MF16
#undef RDBF
#undef RDA
#undef BOFF
#undef AOFF
#undef STAGE
}

// ---------------- kernel 5: leaf path products ------------------------------
// dp [b, t*256+d] bf16 decision probs -> lp [b, t*256+m] bf16 (m = folded leaf)
// factor(n,m): dec = (1<<n)-1 + (m>>(8-n)), side = (m>>(7-n))&1
__global__ __launch_bounds__(256) void leafprod_k(const u16* __restrict__ dp,
                                                  u16* __restrict__ lp) {
    __shared__ float P[4][256];
    int wid = threadIdx.x >> 6, lane = threadIdx.x & 63;
    int idx = blockIdx.x * 4 + wid;          // 0..163839 = t*16384 + b
    int t = idx >> 14, b = idx & 16383;
    const u16* row = dp + (size_t)b * K2DIM + t * NPAD;
#pragma unroll
    for (int j = 0; j < 4; ++j)
        P[wid][lane + 64 * j] = bf2f(row[lane + 64 * j]);
    __syncthreads();
#pragma unroll
    for (int j = 0; j < 4; ++j) {
        int m = lane + 64 * j;
        float prod = 1.0f;
#pragma unroll
        for (int n = 0; n < 8; ++n) {
            int dec  = (1 << n) - 1 + (m >> (8 - n));
            int side = (m >> (7 - n)) & 1;
            float p  = P[wid][dec];
            prod *= side ? (1.0f - p) : p;
        }
        lp[(size_t)b * K2DIM + t * NPAD + m] = f2bf(prod);
    }
}

// ---------------- launch -----------------------------------------------------
extern "C" void kernel_launch(void* const* d_in, const int* in_sizes, int n_in,
                              void* d_out, int out_size, void* d_ws, size_t ws_size,
                              hipStream_t stream) {
    const float* x   = (const float*)d_in[0];
    const float* w_d = (const float*)d_in[1];
    const float* w_l = (const float*)d_in[2];
    float* out = (float*)d_out;

    // workspace layout (173,015,040 B total, with aliasing):
    //   [0, 5.24MB)        B2t  (alive softmax..gemm2)
    //   region = +5.24MB, 83.9MB:
    //       xb (67.1MB) | wdT (10.5MB) | B2 (5.24MB)   -- dead after gemm1
    //       lp (83.9MB) aliases the region, written after gemm1
    //   [+89.1MB, +173MB)  dp (83.9MB)
    char* w = (char*)d_ws;
    u16* B2t = (u16*)w;
    char* region = w + 5242880;
    u16* xb  = (u16*)region;
    u16* wdT = (u16*)(region + 67108864);
    u16* B2  = (u16*)(region + 67108864 + 10485760);
    u16* lp  = (u16*)region;
    u16* dp  = (u16*)(region + 83886080);

    cast_x_k<<<32768, 256, 0, stream>>>((const float4*)x, (uint2*)xb);
    transpose_wd_k<<<dim3(64, 8, T_TREES), dim3(32, 8), 0, stream>>>(w_d, wdT);
    softmax_fold_k<<<640, 256, 0, stream>>>(w_l, B2);
    transpose_b2_k<<<dim3(80, 32), dim3(32, 8), 0, stream>>>(B2, B2t);
    // GEMM1 (phased 256^2): [16384,2048] x [2560,2048]^T -> sigmoid -> dp bf16
    gemm8p<32, 0><<<dim3(64, 10), 512, 0, stream>>>(xb, wdT, dp);
    leafprod_k<<<40960, 256, 0, stream>>>(dp, lp);
    // GEMM2 (phased 256^2): [16384,2560] x [1024,2560]^T -> out fp32 (cols<1000)
    gemm8p<40, 1><<<dim3(64, 4), 512, 0, stream>>>(lp, B2t, out);
}

// Round 3
// 515.882 us; speedup vs baseline: 1.1060x; 1.0128x over previous
//
#include <hip/hip_runtime.h>
#include <stdint.h>

// ---------------- problem constants ----------------
#define T_TREES 10
#define IN_DIM  2048
#define BATCH   16384
#define CLASSES 1000
#define NDEC    255
#define NPAD    256          // decisions padded to 256
#define K2DIM   (T_TREES * NPAD)  // 2560
#define NPADC   1024         // classes padded to 1024

typedef unsigned short u16;
typedef float floatx4 __attribute__((ext_vector_type(4)));
typedef __bf16 bf16x8 __attribute__((ext_vector_type(8)));

// ---------------- helpers ----------------
__device__ __forceinline__ u16 f2bf(float f) {
    union { float f; uint32_t u; } v; v.f = f;
    uint32_t u = v.u;
    return (u16)((u + 0x7FFFu + ((u >> 16) & 1u)) >> 16);   // RNE
}
__device__ __forceinline__ float bf2f(u16 h) {
    union { uint32_t u; float f; } v; v.u = ((uint32_t)h) << 16;
    return v.f;
}

// async global->LDS, 16B per lane. LDS dest is wave-uniform base; HW writes
// lane i at base + i*16.
__device__ __forceinline__ void gld16(u16* lds_p, const u16* g) {
    __builtin_amdgcn_global_load_lds(
        (__attribute__((address_space(1))) const void*)g,
        (__attribute__((address_space(3))) void*)lds_p,
        16, 0, 0);
}

// ---------------- kernel 0: x fp32 -> bf16 ----------------
__global__ __launch_bounds__(256) void cast_x_k(const float4* __restrict__ x,
                                                uint2* __restrict__ xb) {
    int i = blockIdx.x * 256 + threadIdx.x;   // grid sized exactly
    float4 v = x[i];
    uint2 o;
    o.x = (uint32_t)f2bf(v.x) | ((uint32_t)f2bf(v.y) << 16);
    o.y = (uint32_t)f2bf(v.z) | ((uint32_t)f2bf(v.w) << 16);
    xb[i] = o;
}

// ---------------- kernel 1: w_d [t,i,255] fp32 -> wdT [t,256,2048] bf16 ----
__global__ void transpose_wd_k(const float* __restrict__ wd, u16* __restrict__ wdT) {
    __shared__ float tile[32][33];
    int tx = threadIdx.x, ty = threadIdx.y;
    int t = blockIdx.z;
    int i0 = blockIdx.x * 32, d0 = blockIdx.y * 32;
#pragma unroll
    for (int r = 0; r < 4; ++r) {
        int i = i0 + ty + r * 8;
        int d = d0 + tx;
        float v = (d < NDEC) ? wd[((size_t)t * IN_DIM + i) * NDEC + d] : 0.0f;
        tile[ty + r * 8][tx] = v;
    }
    __syncthreads();
#pragma unroll
    for (int r = 0; r < 4; ++r) {
        int dd = d0 + ty + r * 8;
        int ii = i0 + tx;
        wdT[((size_t)t * NPAD + dd) * IN_DIM + ii] = f2bf(tile[tx][ty + r * 8]);
    }
}

// ------- kernel 2: softmax(w_l) rows, fold leaf pairs, *0.1 -> B2 [2560,1024] bf16
__global__ __launch_bounds__(256) void softmax_fold_k(const float* __restrict__ wl,
                                                      u16* __restrict__ B2) {
    int wid = threadIdx.x >> 6, lane = threadIdx.x & 63;
    int idx = blockIdx.x * 4 + wid;          // 0..2559 = t*256 + m
    int t = idx >> 8, m = idx & 255;
    const float* r0 = wl + ((size_t)t * 512 + 2 * m) * CLASSES;
    const float* r1 = r0 + CLASSES;
    float v0[16], v1[16];
    float mx0 = -3.0e38f, mx1 = -3.0e38f;
#pragma unroll
    for (int j = 0; j < 16; ++j) {
        int c = lane + 64 * j;
        float a = (c < CLASSES) ? r0[c] : -3.0e38f;
        float b = (c < CLASSES) ? r1[c] : -3.0e38f;
        v0[j] = a; v1[j] = b;
        mx0 = fmaxf(mx0, a); mx1 = fmaxf(mx1, b);
    }
#pragma unroll
    for (int o = 32; o > 0; o >>= 1) {
        mx0 = fmaxf(mx0, __shfl_xor(mx0, o));
        mx1 = fmaxf(mx1, __shfl_xor(mx1, o));
    }
    float s0 = 0.f, s1 = 0.f;
#pragma unroll
    for (int j = 0; j < 16; ++j) {
        int c = lane + 64 * j;
        float e0 = (c < CLASSES) ? __expf(v0[j] - mx0) : 0.f;
        float e1 = (c < CLASSES) ? __expf(v1[j] - mx1) : 0.f;
        v0[j] = e0; v1[j] = e1; s0 += e0; s1 += e1;
    }
#pragma unroll
    for (int o = 32; o > 0; o >>= 1) { s0 += __shfl_xor(s0, o); s1 += __shfl_xor(s1, o); }
    float i0 = 0.1f / s0, i1 = 0.1f / s1;
#pragma unroll
    for (int j = 0; j < 16; ++j) {
        int c = lane + 64 * j;               // covers 0..1023 exactly
        float v = (c < CLASSES) ? (v0[j] * i0 + v1[j] * i1) : 0.f;
        B2[(size_t)idx * NPADC + c] = f2bf(v);
    }
}

// ---------------- kernel 3: B2 [2560,1024] -> B2t [1024,2560] bf16 ----------
__global__ void transpose_b2_k(const u16* __restrict__ B2, u16* __restrict__ B2t) {
    __shared__ u16 tile[32][33];
    int tx = threadIdx.x, ty = threadIdx.y;
    int k0 = blockIdx.x * 32, c0 = blockIdx.y * 32;
#pragma unroll
    for (int r = 0; r < 4; ++r)
        tile[ty + r * 8][tx] = B2[(size_t)(k0 + ty + r * 8) * NPADC + c0 + tx];
    __syncthreads();
#pragma unroll
    for (int r = 0; r < 4; ++r)
        B2t[(size_t)(c0 + ty + r * 8) * K2DIM + k0 + tx] = tile[tx][ty + r * 8];
}

// ======================================================================
// 128x256-tile, BK=32, 8-wave (2Mx4N, 64x64 per wave), 2-phase/tile GEMM.
// C = A[M,K] @ B[N,K]^T.
//   EPI=0 (GEMM1): blockIdx.y = tree; epilogue = sigmoid -> LDS ->
//                  leaf-product tree expansion -> lp bf16 (fused leafprod).
//   EPI=1 (GEMM2): fp32 store, cols < CLASSES.
//
// Occupancy design: acc[4][4]=64 regs + frags ~40 -> <=128 VGPR/wave
// (__launch_bounds__(512,4)) -> 4 waves/SIMD -> TWO blocks/CU. Cross-block
// TLP hides each block's ds_read + barrier serial sections under the other
// block's MFMA (the m97 mechanism), instead of 1 barrier-locked block.
//
// LDS 48 KiB: Ab[2] 128x32 (8 KB each), Bb[2] 256x32 (16 KB each).
// At BK=32 a fragment ds_read_b128 covers contiguous 1 KiB per wave and
// staging is linear -> zero bank conflicts, NO swizzle needed anywhere.
//
// Per tile t (parity P=t&1), 2 phases:
//  P0: rd aF0,aF1 + bF[0..3] (6); stage A(t+1)->Ab[1-P] (1 gld16);
//      BAR; lgkm(0); 8 MFMA (mi0,1); BAR;
//  P1: rd aF2,aF3 (2); stage B(t+2)->Bb[P] (2 gld16); WAITVM(2);
//      BAR; lgkm(0); 8 MFMA (mi2,3); BAR;
// vmcnt ledger (per wave: A=1 issue, B=2): steady in-flight before the
// wait = B(t+1)[2]+A(t+1)[1]+B(t+2)[2]=5 -> WAITVM(2) retires A(t+1),
// B(t+1), leaves B(t+2). Hazards: Ab[1-P] last read at t-1 P1 (lgkm-
// drained + barrier before t P0 issue); Bb[P] reads issued t P0, drained
// at t P0 lgkm(0) + barrier before t P1 stage issue. Tail: tile NT-2
// stages A only + WAITVM(0); tile NT-1 stages nothing.
// ======================================================================

#define WAITLGKM_(n) asm volatile("s_waitcnt lgkmcnt(" #n ")" ::: "memory")
#define WAITLGKM(n) WAITLGKM_(n)
#define WAITVM_(n) asm volatile("s_waitcnt vmcnt(" #n ")" ::: "memory")
#define WAITVM(n) WAITVM_(n)
#define SB  __builtin_amdgcn_sched_barrier(0)
#define BAR __builtin_amdgcn_s_barrier()

template<int NT, int EPI>
__global__ __launch_bounds__(512, 4) void gemmF(const u16* __restrict__ A,
                                                const u16* __restrict__ B,
                                                void* __restrict__ Cout) {
    constexpr int K = NT * 32;
    // EPI0 epilogue needs 128x256 bf16 = 64 KiB; main loop needs 48 KiB.
    __shared__ __align__(16) u16 lds[(EPI == 0) ? 32768 : 24576];

    const int tid  = threadIdx.x;
    const int wid  = tid >> 6;
    const int lane = tid & 63;
    const int wm = wid >> 2, wn = wid & 3;      // 2 x 4 wave grid
    const int quad = lane >> 4, t16 = lane & 15;

    const size_t m0 = (size_t)blockIdx.x * 128;
    const u16* __restrict__ Ag = A + m0 * (size_t)K;
    const u16* __restrict__ Bg = B + (size_t)blockIdx.y * 256 * (size_t)K;

    // staging per-lane src: row = wid*16 + lane/4, 16B seg = lane%3..; linear
    const uint32_t stRow = (uint32_t)(wid * 16 + (lane >> 2));
    const uint32_t stSeg = (uint32_t)((lane & 3) * 8);
    const u16* pa  = Ag + (size_t)stRow * K + stSeg;
    const u16* pb0 = Bg + (size_t)stRow * K + stSeg;
    const u16* pb1 = pb0 + (size_t)128 * K;
    u16* const ldsA = &lds[wid * 512];           // wave-uniform dests
    u16* const ldsB = &lds[8192 + wid * 512];

#define STAGEA(par, koff) gld16(ldsA + (par) * 4096, pa + (koff))
#define STAGEB(par, koff) do { \
    gld16(ldsB + (par) * 8192,        pb0 + (koff)); \
    gld16(ldsB + (par) * 8192 + 4096, pb1 + (koff)); \
  } while (0)

    // fragment element offsets (contiguous 1 KiB per wave-read)
#define AOFF(P, mi) ((P) * 4096 + (wm * 64 + (mi) * 16 + t16) * 32 + quad * 8)
#define BOFF(P, ni) (8192 + (P) * 8192 + (wn * 64 + (ni) * 16 + t16) * 32 + quad * 8)

#define MF8(mb, a0_, a1_) do { \
    _Pragma("unroll") \
    for (int ni_ = 0; ni_ < 4; ++ni_) { \
      acc[(mb)][ni_]     = __builtin_amdgcn_mfma_f32_16x16x32_bf16( \
          a0_, bF[ni_], acc[(mb)][ni_], 0, 0, 0); \
      acc[(mb) + 1][ni_] = __builtin_amdgcn_mfma_f32_16x16x32_bf16( \
          a1_, bF[ni_], acc[(mb) + 1][ni_], 0, 0, 0); \
    } \
  } while (0)

    floatx4 acc[4][4];
#pragma unroll
    for (int i = 0; i < 4; ++i)
#pragma unroll
        for (int j = 0; j < 4; ++j) acc[i][j] = (floatx4){0.f, 0.f, 0.f, 0.f};

    bf16x8 aF0, aF1, aF2, aF3, bF[4];

    // ---- prologue: A0->Ab0, B0->Bb0, B1->Bb1 ----
    STAGEA(0, 0);
    STAGEB(0, 0);
    STAGEB(1, 32);
    WAITVM(2);                 // retire A0,B0; B1 (2) in flight
    BAR;

#define TILE(P, t, SA, SBG, HASW, WN) do { \
    aF0   = *(const bf16x8*)&lds[AOFF(P, 0)]; \
    aF1   = *(const bf16x8*)&lds[AOFF(P, 1)]; \
    bF[0] = *(const bf16x8*)&lds[BOFF(P, 0)]; \
    bF[1] = *(const bf16x8*)&lds[BOFF(P, 1)]; \
    bF[2] = *(const bf16x8*)&lds[BOFF(P, 2)]; \
    bF[3] = *(const bf16x8*)&lds[BOFF(P, 3)]; \
    if (SA) { STAGEA(1 - (P), ((t) + 1) * 32); } \
    BAR; WAITLGKM(0); SB; \
    __builtin_amdgcn_s_setprio(1); MF8(0, aF0, aF1); __builtin_amdgcn_s_setprio(0); \
    BAR; \
    aF2 = *(const bf16x8*)&lds[AOFF(P, 2)]; \
    aF3 = *(const bf16x8*)&lds[AOFF(P, 3)]; \
    if (SBG) { STAGEB(P, ((t) + 2) * 32); } \
    if (HASW) { WAITVM(WN); } \
    BAR; WAITLGKM(0); SB; \
    __builtin_amdgcn_s_setprio(1); MF8(2, aF2, aF3); __builtin_amdgcn_s_setprio(0); \
    BAR; \
  } while (0)

    int t = 0;
#pragma unroll 1
    for (int it = 0; it < NT / 2 - 1; ++it, t += 2) {
        TILE(0, t,     true, true, true, 2);
        TILE(1, t + 1, true, true, true, 2);
    }
    TILE(0, NT - 2, true,  false, true,  0);
    TILE(1, NT - 1, false, false, false, 0);

    // ---- epilogue. C/D layout: col = lane&15, row = (lane>>4)*4 + reg ----
    if constexpr (EPI == 0) {
        // fused sigmoid + leaf-product. LDS P[128][256] bf16, col swizzled
        // by ((row>>2)&3)<<4 to spread ds_write banks across quads.
#pragma unroll
        for (int mi = 0; mi < 4; ++mi)
#pragma unroll
            for (int r = 0; r < 4; ++r) {
                const int rl = wm * 64 + mi * 16 + quad * 4 + r;
                const int sw = ((rl >> 2) & 3) << 4;
#pragma unroll
                for (int ni = 0; ni < 4; ++ni) {
                    const int col = wn * 64 + ni * 16 + t16;
                    float v = acc[mi][ni][r];
                    float p = 1.0f / (1.0f + __expf(-v));
                    lds[rl * 256 + (col ^ sw)] = f2bf(p);
                }
            }
        BAR;
        // leaf products: wave handles rows wid*16..+15; lane -> leaves 4l..4l+3
        u16* LP = (u16*)Cout;
#pragma unroll 1
        for (int rr = 0; rr < 16; ++rr) {
            const int rl = wid * 16 + rr;
            const int csw = ((rl >> 2) & 3) << 4;
            const u16* Prow = &lds[rl * 256];
            float pre = 1.0f;
#pragma unroll
            for (int n = 0; n < 6; ++n) {
                const int dec  = (1 << n) - 1 + (lane >> (6 - n));
                const int side = (lane >> (5 - n)) & 1;
                const float p = bf2f(Prow[dec ^ csw]);
                pre *= side ? (1.0f - p) : p;
            }
            const float p6 = bf2f(Prow[(63 + lane) ^ csw]);
            const float e0 = pre * p6, e1 = pre * (1.0f - p6);
            const float pA = bf2f(Prow[(127 + 2 * lane) ^ csw]);
            const float pB = bf2f(Prow[(127 + 2 * lane + 1) ^ csw]);
            ushort4 o;
            o.x = f2bf(e0 * pA); o.y = f2bf(e0 * (1.0f - pA));
            o.z = f2bf(e1 * pB); o.w = f2bf(e1 * (1.0f - pB));
            const size_t row = m0 + rl;
            *(ushort4*)&LP[row * K2DIM + (size_t)blockIdx.y * 256 + 4 * lane] = o;
        }
    } else {
        float* C = (float*)Cout;
        const size_t n0 = (size_t)blockIdx.y * 256;
#pragma unroll
        for (int mi = 0; mi < 4; ++mi)
#pragma unroll
            for (int r = 0; r < 4; ++r) {
                const size_t row = m0 + wm * 64 + mi * 16 + quad * 4 + r;
#pragma unroll
                for (int ni = 0; ni < 4; ++ni) {
                    const int col = (int)n0 + wn * 64 + ni * 16 + t16;
                    if (col < CLASSES)
                        C[row * (size_t)CLASSES + col] = acc[mi][ni][r];
                }
            }
    }
#undef TILE
#undef MF8
#undef BOFF
#undef AOFF
#undef STAGEB
#undef STAGEA
}

// ---------------- launch -----------------------------------------------------
extern "C" void kernel_launch(void* const* d_in, const int* in_sizes, int n_in,
                              void* d_out, int out_size, void* d_ws, size_t ws_size,
                              hipStream_t stream) {
    const float* x   = (const float*)d_in[0];
    const float* w_d = (const float*)d_in[1];
    const float* w_l = (const float*)d_in[2];
    float* out = (float*)d_out;

    // workspace layout (171,966,464 B used of 173,015,040 B; no aliasing):
    //   B2t [0, 5.24MB) | xb 67.1MB | wdT 10.5MB | B2 5.24MB | lp 83.9MB
    char* w = (char*)d_ws;
    u16* B2t = (u16*)w;
    u16* xb  = (u16*)(w + 5242880);
    u16* wdT = (u16*)(w + 5242880 + 67108864);
    u16* B2  = (u16*)(w + 5242880 + 67108864 + 10485760);
    u16* lp  = (u16*)(w + 5242880 + 67108864 + 10485760 + 5242880);

    cast_x_k<<<32768, 256, 0, stream>>>((const float4*)x, (uint2*)xb);
    transpose_wd_k<<<dim3(64, 8, T_TREES), dim3(32, 8), 0, stream>>>(w_d, wdT);
    softmax_fold_k<<<640, 256, 0, stream>>>(w_l, B2);
    transpose_b2_k<<<dim3(80, 32), dim3(32, 8), 0, stream>>>(B2, B2t);
    // GEMM1 + fused sigmoid/leafprod: [16384,2048] x [256,2048]^T per tree
    //   -> lp [16384, 2560] bf16.  Grid 128x10 = 1280 blocks @ 2/CU.
    gemmF<64, 0><<<dim3(128, T_TREES), 512, 0, stream>>>(xb, wdT, lp);
    // GEMM2: [16384,2560] x [1024,2560]^T -> out fp32 (cols<1000).
    //   Grid 128x4 = 512 blocks = exactly 2/CU, zero quantization.
    gemmF<80, 1><<<dim3(128, 4), 512, 0, stream>>>(lp, B2t, out);
}

// Round 4
// 508.544 us; speedup vs baseline: 1.1220x; 1.0144x over previous
//
#include <hip/hip_runtime.h>
#include <stdint.h>

// ---------------- problem constants ----------------
#define T_TREES 10
#define IN_DIM  2048
#define BATCH   16384
#define CLASSES 1000
#define NDEC    255
#define NPAD    256          // decisions padded to 256
#define K2DIM   (T_TREES * NPAD)  // 2560
#define NPADC   1024         // classes padded to 1024

typedef unsigned short u16;
typedef float floatx4 __attribute__((ext_vector_type(4)));
typedef __bf16 bf16x8 __attribute__((ext_vector_type(8)));

// ---------------- helpers ----------------
__device__ __forceinline__ u16 f2bf(float f) {
    union { float f; uint32_t u; } v; v.f = f;
    uint32_t u = v.u;
    return (u16)((u + 0x7FFFu + ((u >> 16) & 1u)) >> 16);   // RNE
}
__device__ __forceinline__ float bf2f(u16 h) {
    union { uint32_t u; float f; } v; v.u = ((uint32_t)h) << 16;
    return v.f;
}

// async global->LDS, 16B per lane. LDS dest is wave-uniform base; HW writes
// lane i at base + i*16.
__device__ __forceinline__ void gld16(u16* lds_p, const u16* g) {
    __builtin_amdgcn_global_load_lds(
        (__attribute__((address_space(1))) const void*)g,
        (__attribute__((address_space(3))) void*)lds_p,
        16, 0, 0);
}

// ---------------- kernel 0: x fp32 -> bf16 ----------------
__global__ __launch_bounds__(256) void cast_x_k(const float4* __restrict__ x,
                                                uint2* __restrict__ xb) {
    int i = blockIdx.x * 256 + threadIdx.x;   // grid sized exactly
    float4 v = x[i];
    uint2 o;
    o.x = (uint32_t)f2bf(v.x) | ((uint32_t)f2bf(v.y) << 16);
    o.y = (uint32_t)f2bf(v.z) | ((uint32_t)f2bf(v.w) << 16);
    xb[i] = o;
}

// ---------------- kernel 1: w_d [t,i,255] fp32 -> wdT [t,256,2048] bf16 ----
__global__ void transpose_wd_k(const float* __restrict__ wd, u16* __restrict__ wdT) {
    __shared__ float tile[32][33];
    int tx = threadIdx.x, ty = threadIdx.y;
    int t = blockIdx.z;
    int i0 = blockIdx.x * 32, d0 = blockIdx.y * 32;
#pragma unroll
    for (int r = 0; r < 4; ++r) {
        int i = i0 + ty + r * 8;
        int d = d0 + tx;
        float v = (d < NDEC) ? wd[((size_t)t * IN_DIM + i) * NDEC + d] : 0.0f;
        tile[ty + r * 8][tx] = v;
    }
    __syncthreads();
#pragma unroll
    for (int r = 0; r < 4; ++r) {
        int dd = d0 + ty + r * 8;
        int ii = i0 + tx;
        wdT[((size_t)t * NPAD + dd) * IN_DIM + ii] = f2bf(tile[tx][ty + r * 8]);
    }
}

// ------- kernel 2: softmax(w_l) rows, fold leaf pairs, *0.1 -> B2 [2560,1024] bf16
__global__ __launch_bounds__(256) void softmax_fold_k(const float* __restrict__ wl,
                                                      u16* __restrict__ B2) {
    int wid = threadIdx.x >> 6, lane = threadIdx.x & 63;
    int idx = blockIdx.x * 4 + wid;          // 0..2559 = t*256 + m
    int t = idx >> 8, m = idx & 255;
    const float* r0 = wl + ((size_t)t * 512 + 2 * m) * CLASSES;
    const float* r1 = r0 + CLASSES;
    float v0[16], v1[16];
    float mx0 = -3.0e38f, mx1 = -3.0e38f;
#pragma unroll
    for (int j = 0; j < 16; ++j) {
        int c = lane + 64 * j;
        float a = (c < CLASSES) ? r0[c] : -3.0e38f;
        float b = (c < CLASSES) ? r1[c] : -3.0e38f;
        v0[j] = a; v1[j] = b;
        mx0 = fmaxf(mx0, a); mx1 = fmaxf(mx1, b);
    }
#pragma unroll
    for (int o = 32; o > 0; o >>= 1) {
        mx0 = fmaxf(mx0, __shfl_xor(mx0, o));
        mx1 = fmaxf(mx1, __shfl_xor(mx1, o));
    }
    float s0 = 0.f, s1 = 0.f;
#pragma unroll
    for (int j = 0; j < 16; ++j) {
        int c = lane + 64 * j;
        float e0 = (c < CLASSES) ? __expf(v0[j] - mx0) : 0.f;
        float e1 = (c < CLASSES) ? __expf(v1[j] - mx1) : 0.f;
        v0[j] = e0; v1[j] = e1; s0 += e0; s1 += e1;
    }
#pragma unroll
    for (int o = 32; o > 0; o >>= 1) { s0 += __shfl_xor(s0, o); s1 += __shfl_xor(s1, o); }
    float i0 = 0.1f / s0, i1 = 0.1f / s1;
#pragma unroll
    for (int j = 0; j < 16; ++j) {
        int c = lane + 64 * j;               // covers 0..1023 exactly
        float v = (c < CLASSES) ? (v0[j] * i0 + v1[j] * i1) : 0.f;
        B2[(size_t)idx * NPADC + c] = f2bf(v);
    }
}

// ---------------- kernel 3: B2 [2560,1024] -> B2t [1024,2560] bf16 ----------
__global__ void transpose_b2_k(const u16* __restrict__ B2, u16* __restrict__ B2t) {
    __shared__ u16 tile[32][33];
    int tx = threadIdx.x, ty = threadIdx.y;
    int k0 = blockIdx.x * 32, c0 = blockIdx.y * 32;
#pragma unroll
    for (int r = 0; r < 4; ++r)
        tile[ty + r * 8][tx] = B2[(size_t)(k0 + ty + r * 8) * NPADC + c0 + tx];
    __syncthreads();
#pragma unroll
    for (int r = 0; r < 4; ++r)
        B2t[(size_t)(c0 + ty + r * 8) * K2DIM + k0 + tx] = tile[tx][ty + r * 8];
}

// ======================================================================
// 128x256-tile, BK=32, 8-wave (2Mx4N, 64x64 per wave), 2-phase/tile GEMM.
// C = A[M,K] @ B[N,K]^T.
//   EPI=0 (GEMM1): blockIdx.y = tree; epilogue = sigmoid -> LDS ->
//                  leaf-product tree expansion -> lp bf16 (fused leafprod).
//   EPI=1 (GEMM2): fp32 store, cols < CLASSES.
//
// Occupancy design: acc[4][4]=64 regs + frags -> <=128 VGPR/wave
// (__launch_bounds__(512,4)) -> 4 waves/SIMD -> TWO blocks/CU. Cross-block
// TLP hides each block's ds_read + barrier serial sections under the other
// block's MFMA.
//
// LDS 48 KiB: Ab[2] 128x32 (8 KB each), Bb[2] 256x32 (16 KB each).
//
// BANK SWIZZLE (round-3 fix): rows are 64 B = 4 x 16B segs. Unswizzled,
// a fragment ds_read_b128 (lane (quad,t16) -> row t16, seg quad) gives
// consecutive same-quad lanes only 2 bank-groups (row stride toggles only
// bank bit 4) -> 4-way conflict, measured 2.1e7 cycles. Fix:
//   phys_seg = logical_seg ^ ((row>>1)&3)
// -> bank-group (row&1)*4 + phys_seg is a bijection over 8 groups for any
// 8 consecutive same-quad lanes; uniform 2-way at 16-lane granularity
// (free, m136). Staging applies the inverse on the per-lane GLOBAL seg
// (LDS dest stays linear for global_load_lds):
//   global_seg = (lane&3) ^ ((lane>>3)&3)   [row = wid*16 + lane>>2]
// Read side: seg = quad ^ ((t16>>1)&3)  [row bases are x16 -> only t16
// bits matter].  Same swizzle for A and B tiles.
//
// Per tile t (parity P=t&1), 2 phases:
//  P0: rd aF0,aF1 + bF[0..3] (6); stage A(t+1)->Ab[1-P] (1 gld16);
//      BAR; lgkm(0); 8 MFMA (mi0,1); BAR;
//  P1: rd aF2,aF3 (2); stage B(t+2)->Bb[P] (2 gld16); WAITVM(2);
//      BAR; lgkm(0); 8 MFMA (mi2,3); BAR;
// vmcnt ledger (per wave: A=1 issue, B=2): steady in-flight before the
// wait = B(t+1)[2]+A(t+1)[1]+B(t+2)[2]=5 -> WAITVM(2) retires A(t+1),
// B(t+1), leaves B(t+2). Hazards: Ab[1-P] last read at t-1 P1 (lgkm-
// drained + barrier before t P0 issue); Bb[P] reads issued t P0, drained
// at t P0 lgkm(0) + barrier before t P1 stage issue. Tail: tile NT-2
// stages A only + WAITVM(0); tile NT-1 stages nothing.
// ======================================================================

#define WAITLGKM_(n) asm volatile("s_waitcnt lgkmcnt(" #n ")" ::: "memory")
#define WAITLGKM(n) WAITLGKM_(n)
#define WAITVM_(n) asm volatile("s_waitcnt vmcnt(" #n ")" ::: "memory")
#define WAITVM(n) WAITVM_(n)
#define SB  __builtin_amdgcn_sched_barrier(0)
#define BAR __builtin_amdgcn_s_barrier()

template<int NT, int EPI>
__global__ __launch_bounds__(512, 4) void gemmF(const u16* __restrict__ A,
                                                const u16* __restrict__ B,
                                                void* __restrict__ Cout) {
    constexpr int K = NT * 32;
    // EPI0 epilogue needs 128x256 bf16 = 64 KiB; main loop needs 48 KiB.
    __shared__ __align__(16) u16 lds[(EPI == 0) ? 32768 : 24576];

    const int tid  = threadIdx.x;
    const int wid  = tid >> 6;
    const int lane = tid & 63;
    const int wm = wid >> 2, wn = wid & 3;      // 2 x 4 wave grid
    const int quad = lane >> 4, t16 = lane & 15;

    const size_t m0 = (size_t)blockIdx.x * 128;
    const u16* __restrict__ Ag = A + m0 * (size_t)K;
    const u16* __restrict__ Bg = B + (size_t)blockIdx.y * 256 * (size_t)K;

    // staging per-lane src: row = wid*16 + lane/4; global 16B seg carries the
    // swizzle inverse: (lane&3) ^ ((lane>>3)&3).
    const uint32_t stRow = (uint32_t)(wid * 16 + (lane >> 2));
    const uint32_t stSeg = (uint32_t)(((lane & 3) ^ ((lane >> 3) & 3)) * 8);
    const u16* pa  = Ag + (size_t)stRow * K + stSeg;
    const u16* pb0 = Bg + (size_t)stRow * K + stSeg;
    const u16* pb1 = pb0 + (size_t)128 * K;
    u16* const ldsA = &lds[wid * 512];           // wave-uniform dests
    u16* const ldsB = &lds[8192 + wid * 512];

#define STAGEA(par, koff) gld16(ldsA + (par) * 4096, pa + (koff))
#define STAGEB(par, koff) do { \
    gld16(ldsB + (par) * 8192,        pb0 + (koff)); \
    gld16(ldsB + (par) * 8192 + 4096, pb1 + (koff)); \
  } while (0)

    // fragment element offsets; swizzled seg = quad ^ ((t16>>1)&3)
    const int rsw = ((quad ^ ((t16 >> 1) & 3)) * 8);
#define AOFF(P, mi) ((P) * 4096 + (wm * 64 + (mi) * 16 + t16) * 32 + rsw)
#define BOFF(P, ni) (8192 + (P) * 8192 + (wn * 64 + (ni) * 16 + t16) * 32 + rsw)

#define MF8(mb, a0_, a1_) do { \
    _Pragma("unroll") \
    for (int ni_ = 0; ni_ < 4; ++ni_) { \
      acc[(mb)][ni_]     = __builtin_amdgcn_mfma_f32_16x16x32_bf16( \
          a0_, bF[ni_], acc[(mb)][ni_], 0, 0, 0); \
      acc[(mb) + 1][ni_] = __builtin_amdgcn_mfma_f32_16x16x32_bf16( \
          a1_, bF[ni_], acc[(mb) + 1][ni_], 0, 0, 0); \
    } \
  } while (0)

    floatx4 acc[4][4];
#pragma unroll
    for (int i = 0; i < 4; ++i)
#pragma unroll
        for (int j = 0; j < 4; ++j) acc[i][j] = (floatx4){0.f, 0.f, 0.f, 0.f};

    bf16x8 aF0, aF1, aF2, aF3, bF[4];

    // ---- prologue: A0->Ab0, B0->Bb0, B1->Bb1 ----
    STAGEA(0, 0);
    STAGEB(0, 0);
    STAGEB(1, 32);
    WAITVM(2);                 // retire A0,B0; B1 (2) in flight
    BAR;

#define TILE(P, t, SA, SBG, HASW, WN) do { \
    aF0   = *(const bf16x8*)&lds[AOFF(P, 0)]; \
    aF1   = *(const bf16x8*)&lds[AOFF(P, 1)]; \
    bF[0] = *(const bf16x8*)&lds[BOFF(P, 0)]; \
    bF[1] = *(const bf16x8*)&lds[BOFF(P, 1)]; \
    bF[2] = *(const bf16x8*)&lds[BOFF(P, 2)]; \
    bF[3] = *(const bf16x8*)&lds[BOFF(P, 3)]; \
    if (SA) { STAGEA(1 - (P), ((t) + 1) * 32); } \
    BAR; WAITLGKM(0); SB; \
    __builtin_amdgcn_s_setprio(1); MF8(0, aF0, aF1); __builtin_amdgcn_s_setprio(0); \
    BAR; \
    aF2 = *(const bf16x8*)&lds[AOFF(P, 2)]; \
    aF3 = *(const bf16x8*)&lds[AOFF(P, 3)]; \
    if (SBG) { STAGEB(P, ((t) + 2) * 32); } \
    if (HASW) { WAITVM(WN); } \
    BAR; WAITLGKM(0); SB; \
    __builtin_amdgcn_s_setprio(1); MF8(2, aF2, aF3); __builtin_amdgcn_s_setprio(0); \
    BAR; \
  } while (0)

    int t = 0;
#pragma unroll 1
    for (int it = 0; it < NT / 2 - 1; ++it, t += 2) {
        TILE(0, t,     true, true, true, 2);
        TILE(1, t + 1, true, true, true, 2);
    }
    TILE(0, NT - 2, true,  false, true,  0);
    TILE(1, NT - 1, false, false, false, 0);

    // ---- epilogue. C/D layout: col = lane&15, row = (lane>>4)*4 + reg ----
    if constexpr (EPI == 0) {
        // fused sigmoid + leaf-product. LDS P[128][256] bf16, col swizzled
        // by ((row>>2)&3)<<4 to spread ds_write banks across quads.
#pragma unroll
        for (int mi = 0; mi < 4; ++mi)
#pragma unroll
            for (int r = 0; r < 4; ++r) {
                const int rl = wm * 64 + mi * 16 + quad * 4 + r;
                const int sw = ((rl >> 2) & 3) << 4;
#pragma unroll
                for (int ni = 0; ni < 4; ++ni) {
                    const int col = wn * 64 + ni * 16 + t16;
                    float v = acc[mi][ni][r];
                    float p = 1.0f / (1.0f + __expf(-v));
                    lds[rl * 256 + (col ^ sw)] = f2bf(p);
                }
            }
        BAR;
        // leaf products: wave handles rows wid*16..+15; lane -> leaves 4l..4l+3
        u16* LP = (u16*)Cout;
#pragma unroll 1
        for (int rr = 0; rr < 16; ++rr) {
            const int rl = wid * 16 + rr;
            const int csw = ((rl >> 2) & 3) << 4;
            const u16* Prow = &lds[rl * 256];
            float pre = 1.0f;
#pragma unroll
            for (int n = 0; n < 6; ++n) {
                const int dec  = (1 << n) - 1 + (lane >> (6 - n));
                const int side = (lane >> (5 - n)) & 1;
                const float p = bf2f(Prow[dec ^ csw]);
                pre *= side ? (1.0f - p) : p;
            }
            const float p6 = bf2f(Prow[(63 + lane) ^ csw]);
            const float e0 = pre * p6, e1 = pre * (1.0f - p6);
            const float pA = bf2f(Prow[(127 + 2 * lane) ^ csw]);
            const float pB = bf2f(Prow[(127 + 2 * lane + 1) ^ csw]);
            ushort4 o;
            o.x = f2bf(e0 * pA); o.y = f2bf(e0 * (1.0f - pA));
            o.z = f2bf(e1 * pB); o.w = f2bf(e1 * (1.0f - pB));
            const size_t row = m0 + rl;
            *(ushort4*)&LP[row * K2DIM + (size_t)blockIdx.y * 256 + 4 * lane] = o;
        }
    } else {
        float* C = (float*)Cout;
        const size_t n0 = (size_t)blockIdx.y * 256;
#pragma unroll
        for (int mi = 0; mi < 4; ++mi)
#pragma unroll
            for (int r = 0; r < 4; ++r) {
                const size_t row = m0 + wm * 64 + mi * 16 + quad * 4 + r;
#pragma unroll
                for (int ni = 0; ni < 4; ++ni) {
                    const int col = (int)n0 + wn * 64 + ni * 16 + t16;
                    if (col < CLASSES)
                        C[row * (size_t)CLASSES + col] = acc[mi][ni][r];
                }
            }
    }
#undef TILE
#undef MF8
#undef BOFF
#undef AOFF
#undef STAGEB
#undef STAGEA
}

// ---------------- launch -----------------------------------------------------
extern "C" void kernel_launch(void* const* d_in, const int* in_sizes, int n_in,
                              void* d_out, int out_size, void* d_ws, size_t ws_size,
                              hipStream_t stream) {
    const float* x   = (const float*)d_in[0];
    const float* w_d = (const float*)d_in[1];
    const float* w_l = (const float*)d_in[2];
    float* out = (float*)d_out;

    // workspace layout (171,966,464 B used of 173,015,040 B; no aliasing):
    //   B2t [0, 5.24MB) | xb 67.1MB | wdT 10.5MB | B2 5.24MB | lp 83.9MB
    char* w = (char*)d_ws;
    u16* B2t = (u16*)w;
    u16* xb  = (u16*)(w + 5242880);
    u16* wdT = (u16*)(w + 5242880 + 67108864);
    u16* B2  = (u16*)(w + 5242880 + 67108864 + 10485760);
    u16* lp  = (u16*)(w + 5242880 + 67108864 + 10485760 + 5242880);

    cast_x_k<<<32768, 256, 0, stream>>>((const float4*)x, (uint2*)xb);
    transpose_wd_k<<<dim3(64, 8, T_TREES), dim3(32, 8), 0, stream>>>(w_d, wdT);
    softmax_fold_k<<<640, 256, 0, stream>>>(w_l, B2);
    transpose_b2_k<<<dim3(80, 32), dim3(32, 8), 0, stream>>>(B2, B2t);
    // GEMM1 + fused sigmoid/leafprod: [16384,2048] x [256,2048]^T per tree
    //   -> lp [16384, 2560] bf16.  Grid 128x10 = 1280 blocks @ 2/CU.
    gemmF<64, 0><<<dim3(128, T_TREES), 512, 0, stream>>>(xb, wdT, lp);
    // GEMM2: [16384,2560] x [1024,2560]^T -> out fp32 (cols<1000).
    //   Grid 128x4 = 512 blocks = exactly 2/CU, zero quantization.
    gemmF<80, 1><<<dim3(128, 4), 512, 0, stream>>>(lp, B2t, out);
}